// Round 1
// baseline (846.545 us; speedup 1.0000x reference)
//
#include <hip/hip_runtime.h>
#include <hip/hip_bf16.h>

// ---------------- problem constants (fixed by reference) ----------------
constexpr int NT = 4096;   // tokens = B*S = 2*2048
constexpr int DD = 768;    // model dim
constexpr int FF = 2048;   // ffn dim
constexpr int NE = 8;      // experts
constexpr int MAXROWS = 8704;   // padded assignment rows cap (8192 + 8*63 rounded)
constexpr int MAXTILES = 136;   // MAXROWS/64

// meta layout (int indices into ws[0..1024))
constexpr int IDX_CNTA   = 0;   // [8]  assignments per expert
constexpr int IDX_CNTT1  = 8;   // [8]  top-1 counts (load)
constexpr int IDX_CUR    = 16;  // [8]  scatter cursors
constexpr int IDX_IMP    = 24;  // [8]  float: sum of probs per expert
constexpr int IDX_ZSUM   = 32;  // float: sum logits^2
constexpr int IDX_NTILES = 33;
constexpr int IDX_OFF    = 34;  // [9]  64-aligned segment offsets
constexpr int IDX_EXPT   = 48;  // [MAXTILES] tile -> expert

// ws byte offsets (all 256-aligned)
constexpr size_t OFF_META   = 0;
constexpr size_t OFF_TKE    = 1024;                         // int [NT][2]
constexpr size_t OFF_GATE   = OFF_TKE    + (size_t)NT*2*4;  // float [NT][2]
constexpr size_t OFF_ROWOF  = OFF_GATE   + (size_t)NT*2*4;  // int [NT][2]
constexpr size_t OFF_TOKROW = OFF_ROWOF  + (size_t)NT*2*4;  // int [MAXROWS]
constexpr size_t OFF_XG     = 134144;                       // bf16 [MAXROWS][DD]
constexpr size_t OFF_W1T    = OFF_XG  + (size_t)MAXROWS*DD*2;      // bf16 [NE][FF][DD]
constexpr size_t OFF_W3T    = OFF_W1T + (size_t)NE*FF*DD*2;
constexpr size_t OFF_W2T    = OFF_W3T + (size_t)NE*FF*DD*2;        // bf16 [NE][DD][FF]
constexpr size_t OFF_H      = OFF_W2T + (size_t)NE*FF*DD*2;        // bf16 [MAXROWS][FF]
constexpr size_t OFF_OP     = OFF_H   + (size_t)MAXROWS*FF*2;      // bf16 [MAXROWS][DD]

typedef float f32x4 __attribute__((ext_vector_type(4)));
typedef __bf16 bf16x8v __attribute__((ext_vector_type(8)));

// ---------------- router: fp32-exact logits, softmax, top-2 ----------------
__global__ __launch_bounds__(256) void router_kernel(const float* __restrict__ x,
    const float* __restrict__ rw, int* __restrict__ meta,
    int* __restrict__ tke, float* __restrict__ gateArr) {
  const int wave = threadIdx.x >> 6, lane = threadIdx.x & 63;
  const int t = blockIdx.x * 4 + wave;
  float acc[NE];
  #pragma unroll
  for (int e = 0; e < NE; ++e) acc[e] = 0.f;
  const float* xr = x + (size_t)t * DD;
  for (int i = lane; i < DD; i += 64) {
    float xv = xr[i];
    const float* r = rw + i * NE;
    #pragma unroll
    for (int e = 0; e < NE; ++e) acc[e] += xv * r[e];
  }
  #pragma unroll
  for (int off = 32; off > 0; off >>= 1) {
    #pragma unroll
    for (int e = 0; e < NE; ++e) acc[e] += __shfl_xor(acc[e], off);
  }
  // softmax (all lanes redundantly)
  float mx = acc[0];
  #pragma unroll
  for (int e = 1; e < NE; ++e) mx = fmaxf(mx, acc[e]);
  float p[NE]; float s = 0.f;
  #pragma unroll
  for (int e = 0; e < NE; ++e) { p[e] = __expf(acc[e] - mx); s += p[e]; }
  float inv = 1.f / s;
  #pragma unroll
  for (int e = 0; e < NE; ++e) p[e] *= inv;
  // top-2, first-index-on-tie (matches jax.lax.top_k)
  int e0 = 0; float p0 = p[0];
  #pragma unroll
  for (int e = 1; e < NE; ++e) if (p[e] > p0) { p0 = p[e]; e0 = e; }
  int e1 = -1; float p1 = -1.f;
  #pragma unroll
  for (int e = 0; e < NE; ++e) if (e != e0 && p[e] > p1) { p1 = p[e]; e1 = e; }
  float z = 0.f;
  #pragma unroll
  for (int e = 0; e < NE; ++e) z += acc[e] * acc[e];
  if (lane == 0) {
    float* fmeta = (float*)meta;
    #pragma unroll
    for (int e = 0; e < NE; ++e) atomicAdd(&fmeta[IDX_IMP + e], p[e]);
    atomicAdd(&fmeta[IDX_ZSUM], z);
    atomicAdd(&meta[IDX_CNTT1 + e0], 1);
    atomicAdd(&meta[IDX_CNTA + e0], 1);
    atomicAdd(&meta[IDX_CNTA + e1], 1);
    float gs = 1.f / (p0 + p1);
    tke[t*2]   = e0; tke[t*2+1] = e1;
    gateArr[t*2] = p0 * gs; gateArr[t*2+1] = p1 * gs;
  }
}

// ---------------- scan: segment offsets + losses (1 thread, trivial work) --
__global__ void scan_kernel(int* __restrict__ meta, float* __restrict__ out_tail) {
  if (threadIdx.x != 0 || blockIdx.x != 0) return;
  float* fmeta = (float*)meta;
  int off = 0, tidx = 0;
  for (int e = 0; e < NE; ++e) {
    meta[IDX_OFF + e] = off;
    int ntile = (meta[IDX_CNTA + e] + 63) >> 6;
    for (int i = 0; i < ntile; ++i) meta[IDX_EXPT + tidx++] = e;
    off += ntile << 6;
  }
  meta[IDX_OFF + NE] = off;
  meta[IDX_NTILES] = tidx;
  float aux = 0.f;
  for (int e = 0; e < NE; ++e)
    aux += (fmeta[IDX_IMP + e] / (float)NT) * ((float)meta[IDX_CNTT1 + e] / (float)NT);
  out_tail[0] = (float)NE * aux * 0.01f;
  out_tail[1] = fmeta[IDX_ZSUM] / (float)(NT * NE) * 0.001f;
}

// ---------------- scatter: token -> padded row mapping ----------------
__global__ __launch_bounds__(256) void scatter_kernel(const int* __restrict__ tke,
    int* __restrict__ meta, int* __restrict__ rowof, int* __restrict__ tokrow) {
  int t = blockIdx.x * 256 + threadIdx.x;
  if (t >= NT) return;
  #pragma unroll
  for (int s = 0; s < 2; ++s) {
    int e = tke[t*2 + s];
    int pos = atomicAdd(&meta[IDX_CUR + e], 1);
    int row = meta[IDX_OFF + e] + pos;
    rowof[t*2 + s] = row;
    tokrow[row] = t;
  }
}

// ---------------- gather x rows -> bf16 Xg (zeros for padding) ------------
__global__ __launch_bounds__(256) void gather_kernel(const float* __restrict__ x,
    const int* __restrict__ tokrow, const int* __restrict__ meta,
    __bf16* __restrict__ Xg) {
  int row = blockIdx.x;
  if (row >= meta[IDX_OFF + NE]) return;
  int tok = tokrow[row];
  __bf16* dst = Xg + (size_t)row * DD;
  if (tok >= 0) {
    const float* src = x + (size_t)tok * DD;
    for (int i = threadIdx.x; i < DD; i += 256) dst[i] = (__bf16)src[i];
  } else {
    for (int i = threadIdx.x; i < DD; i += 256) dst[i] = (__bf16)0.f;
  }
}

// ---------------- transpose + fp32->bf16: [R][C] -> [C][R] ----------------
__global__ __launch_bounds__(256) void transpose_cvt(const float* __restrict__ src,
    __bf16* __restrict__ dst, int R, int C) {
  const size_t eoff = (size_t)blockIdx.z * R * C;
  src += eoff; dst += eoff;
  const int r0 = blockIdx.y * 64, c0 = blockIdx.x * 64;
  __shared__ __bf16 tile[64 * 65];
  const int t = threadIdx.x;
  #pragma unroll
  for (int i = 0; i < 16; ++i) {
    int idx = t + i * 256; int r = idx >> 6, c = idx & 63;
    tile[r * 65 + c] = (__bf16)src[(size_t)(r0 + r) * C + c0 + c];
  }
  __syncthreads();
  #pragma unroll
  for (int i = 0; i < 16; ++i) {
    int idx = t + i * 256; int c = idx >> 6, r = idx & 63;
    dst[(size_t)(c0 + c) * R + r0 + r] = tile[r * 65 + c];
  }
}

// ---------------- gemm1: H = silu(Xg@W1e) * (Xg@W3e) ----------------------
// tile 64Mx64N, K-step 32; A frag: A[m=lane&15][k=quad*8+j] (m120-verified)
__global__ __launch_bounds__(256) void gemm1_kernel(const __bf16* __restrict__ Xg,
    const __bf16* __restrict__ W1t, const __bf16* __restrict__ W3t,
    __bf16* __restrict__ Hb, const int* __restrict__ meta) {
  const int mt = blockIdx.y;
  if (mt >= meta[IDX_NTILES]) return;
  const int e = meta[IDX_EXPT + mt];
  const int n0 = blockIdx.x * 64;
  const int m0 = mt * 64;
  __shared__ __align__(16) __bf16 As[64*32], B1s[64*32], B3s[64*32];
  const int t = threadIdx.x, wave = t >> 6, lane = t & 63;
  const int sr = t >> 2, sc = (t & 3) * 8;  // staging: 16B per thread per tile
  const __bf16* w1e = W1t + (size_t)e * FF * DD;  // [FF][DD]
  const __bf16* w3e = W3t + (size_t)e * FF * DD;
  const f32x4 zero = {0.f, 0.f, 0.f, 0.f};
  f32x4 acc1[4] = {zero, zero, zero, zero};
  f32x4 acc3[4] = {zero, zero, zero, zero};
  for (int k0 = 0; k0 < DD; k0 += 32) {
    *(bf16x8v*)&As[sr*32 + sc]  = *(const bf16x8v*)&Xg [(size_t)(m0 + sr)*DD + k0 + sc];
    *(bf16x8v*)&B1s[sr*32 + sc] = *(const bf16x8v*)&w1e[(size_t)(n0 + sr)*DD + k0 + sc];
    *(bf16x8v*)&B3s[sr*32 + sc] = *(const bf16x8v*)&w3e[(size_t)(n0 + sr)*DD + k0 + sc];
    __syncthreads();
    bf16x8v a = *(const bf16x8v*)&As[(wave*16 + (lane & 15))*32 + (lane >> 4)*8];
    #pragma unroll
    for (int s = 0; s < 4; ++s) {
      bf16x8v b1 = *(const bf16x8v*)&B1s[(s*16 + (lane & 15))*32 + (lane >> 4)*8];
      bf16x8v b3 = *(const bf16x8v*)&B3s[(s*16 + (lane & 15))*32 + (lane >> 4)*8];
      acc1[s] = __builtin_amdgcn_mfma_f32_16x16x32_bf16(a, b1, acc1[s], 0, 0, 0);
      acc3[s] = __builtin_amdgcn_mfma_f32_16x16x32_bf16(a, b3, acc3[s], 0, 0, 0);
    }
    __syncthreads();
  }
  // C/D: row=(lane>>4)*4+r, col=lane&15 (m89-verified)
  const int rowb = m0 + wave*16 + (lane >> 4)*4;
  const int colb = n0 + (lane & 15);
  #pragma unroll
  for (int s = 0; s < 4; ++s) {
    #pragma unroll
    for (int r = 0; r < 4; ++r) {
      float c1 = acc1[s][r], c3 = acc3[s][r];
      float h = c1 / (1.f + __expf(-c1)) * c3;   // silu(c1)*c3
      Hb[(size_t)(rowb + r)*FF + colb + s*16] = (__bf16)h;
    }
  }
}

// ---------------- gemm2: OP = H @ W2e (bf16 partial) ----------------------
__global__ __launch_bounds__(256) void gemm2_kernel(const __bf16* __restrict__ Hb,
    const __bf16* __restrict__ W2t, __bf16* __restrict__ OP,
    const int* __restrict__ meta) {
  const int mt = blockIdx.y;
  if (mt >= meta[IDX_NTILES]) return;
  const int e = meta[IDX_EXPT + mt];
  const int n0 = blockIdx.x * 64;
  const int m0 = mt * 64;
  __shared__ __align__(16) __bf16 As[64*32], Bs[64*32];
  const int t = threadIdx.x, wave = t >> 6, lane = t & 63;
  const int sr = t >> 2, sc = (t & 3) * 8;
  const __bf16* w2e = W2t + (size_t)e * DD * FF;  // [DD][FF]
  const f32x4 zero = {0.f, 0.f, 0.f, 0.f};
  f32x4 acc[4] = {zero, zero, zero, zero};
  for (int k0 = 0; k0 < FF; k0 += 32) {
    *(bf16x8v*)&As[sr*32 + sc] = *(const bf16x8v*)&Hb [(size_t)(m0 + sr)*FF + k0 + sc];
    *(bf16x8v*)&Bs[sr*32 + sc] = *(const bf16x8v*)&w2e[(size_t)(n0 + sr)*FF + k0 + sc];
    __syncthreads();
    bf16x8v a = *(const bf16x8v*)&As[(wave*16 + (lane & 15))*32 + (lane >> 4)*8];
    #pragma unroll
    for (int s = 0; s < 4; ++s) {
      bf16x8v b = *(const bf16x8v*)&Bs[(s*16 + (lane & 15))*32 + (lane >> 4)*8];
      acc[s] = __builtin_amdgcn_mfma_f32_16x16x32_bf16(a, b, acc[s], 0, 0, 0);
    }
    __syncthreads();
  }
  const int rowb = m0 + wave*16 + (lane >> 4)*4;
  const int colb = n0 + (lane & 15);
  #pragma unroll
  for (int s = 0; s < 4; ++s) {
    #pragma unroll
    for (int r = 0; r < 4; ++r)
      OP[(size_t)(rowb + r)*DD + colb + s*16] = (__bf16)acc[s][r];
  }
}

// ---------------- combine: out[t] = g0*OP[row0] + g1*OP[row1] -------------
__global__ __launch_bounds__(256) void combine_kernel(const __bf16* __restrict__ OP,
    const int* __restrict__ rowof, const float* __restrict__ gateArr,
    float* __restrict__ out) {
  const int t = blockIdx.x;
  const int r0 = rowof[t*2], r1 = rowof[t*2 + 1];
  const float g0 = gateArr[t*2], g1 = gateArr[t*2 + 1];
  const __bf16* p0 = OP + (size_t)r0 * DD;
  const __bf16* p1 = OP + (size_t)r1 * DD;
  for (int i = threadIdx.x; i < DD; i += 256)
    out[(size_t)t * DD + i] = g0 * (float)p0[i] + g1 * (float)p1[i];
}

extern "C" void kernel_launch(void* const* d_in, const int* in_sizes, int n_in,
                              void* d_out, int out_size, void* d_ws, size_t ws_size,
                              hipStream_t stream) {
  const float* x  = (const float*)d_in[0];
  const float* rw = (const float*)d_in[1];
  const float* w1 = (const float*)d_in[2];
  const float* w2 = (const float*)d_in[3];
  const float* w3 = (const float*)d_in[4];
  float* out = (float*)d_out;

  char* ws = (char*)d_ws;
  int*    meta   = (int*)(ws + OFF_META);
  int*    tke    = (int*)(ws + OFF_TKE);
  float*  gateA  = (float*)(ws + OFF_GATE);
  int*    rowof  = (int*)(ws + OFF_ROWOF);
  int*    tokrow = (int*)(ws + OFF_TOKROW);
  __bf16* Xg     = (__bf16*)(ws + OFF_XG);
  __bf16* W1t    = (__bf16*)(ws + OFF_W1T);
  __bf16* W3t    = (__bf16*)(ws + OFF_W3T);
  __bf16* W2t    = (__bf16*)(ws + OFF_W2T);
  __bf16* Hb     = (__bf16*)(ws + OFF_H);
  __bf16* OP     = (__bf16*)(ws + OFF_OP);

  hipMemsetAsync(ws + OFF_META, 0, 1024, stream);
  hipMemsetAsync(ws + OFF_TOKROW, 0xFF, (size_t)MAXROWS * 4, stream);  // tok=-1

  // weights -> bf16, K-contiguous ([N][K]) for MFMA B-fragments
  transpose_cvt<<<dim3(FF/64, DD/64, NE), 256, 0, stream>>>(w1, W1t, DD, FF);
  transpose_cvt<<<dim3(FF/64, DD/64, NE), 256, 0, stream>>>(w3, W3t, DD, FF);
  transpose_cvt<<<dim3(DD/64, FF/64, NE), 256, 0, stream>>>(w2, W2t, FF, DD);

  router_kernel<<<NT/4, 256, 0, stream>>>(x, rw, meta, tke, gateA);
  scan_kernel<<<1, 64, 0, stream>>>(meta, out + (size_t)NT * DD);
  scatter_kernel<<<(NT + 255)/256, 256, 0, stream>>>(tke, meta, rowof, tokrow);
  gather_kernel<<<MAXROWS, 256, 0, stream>>>(x, tokrow, meta, Xg);

  gemm1_kernel<<<dim3(FF/64, MAXTILES), 256, 0, stream>>>(Xg, W1t, W3t, Hb, meta);
  gemm2_kernel<<<dim3(DD/64, MAXTILES), 256, 0, stream>>>(Hb, W2t, OP, meta);
  combine_kernel<<<NT, 256, 0, stream>>>(OP, rowof, gateA, out);
}

// Round 2
// 428.189 us; speedup vs baseline: 1.9770x; 1.9770x over previous
//
#include <hip/hip_runtime.h>
#include <hip/hip_bf16.h>

// ---------------- problem constants (fixed by reference) ----------------
constexpr int NT = 4096;   // tokens = B*S = 2*2048
constexpr int DD = 768;    // model dim
constexpr int FF = 2048;   // ffn dim
constexpr int NE = 8;      // experts
constexpr int MAXROWS = 8704;   // padded assignment rows cap (8192 + 8*63 rounded)
constexpr int MAXTILES = 136;   // MAXROWS/64

// meta layout (int indices into ws[0..1024))
constexpr int IDX_CNTA   = 0;   // [8]  assignments per expert
constexpr int IDX_CNTT1  = 8;   // [8]  top-1 counts (load)
constexpr int IDX_CUR    = 16;  // [8]  scatter cursors
constexpr int IDX_IMP    = 24;  // [8]  float: sum of probs per expert
constexpr int IDX_ZSUM   = 32;  // float: sum logits^2
constexpr int IDX_NTILES = 33;
constexpr int IDX_OFF    = 34;  // [9]  64-aligned segment offsets
constexpr int IDX_EXPT   = 48;  // [MAXTILES] tile -> expert

// ws byte offsets (all 256-aligned)
constexpr size_t OFF_META   = 0;
constexpr size_t OFF_TKE    = 1024;                         // int [NT][2]
constexpr size_t OFF_GATE   = OFF_TKE    + (size_t)NT*2*4;  // float [NT][2]
constexpr size_t OFF_ROWOF  = OFF_GATE   + (size_t)NT*2*4;  // int [NT][2]
constexpr size_t OFF_TOKROW = OFF_ROWOF  + (size_t)NT*2*4;  // int [MAXROWS]
constexpr size_t OFF_XG     = 134144;                       // bf16 [MAXROWS][DD]
constexpr size_t OFF_W1T    = OFF_XG  + (size_t)MAXROWS*DD*2;      // bf16 [NE][FF][DD]
constexpr size_t OFF_W3T    = OFF_W1T + (size_t)NE*FF*DD*2;
constexpr size_t OFF_W2T    = OFF_W3T + (size_t)NE*FF*DD*2;        // bf16 [NE][DD][FF]
constexpr size_t OFF_H      = OFF_W2T + (size_t)NE*FF*DD*2;        // bf16 [MAXROWS][FF]
constexpr size_t OFF_OP     = OFF_H   + (size_t)MAXROWS*FF*2;      // bf16 [MAXROWS][DD]

typedef float f32x4 __attribute__((ext_vector_type(4)));
typedef __bf16 bf16x8v __attribute__((ext_vector_type(8)));

__device__ inline unsigned short f2bf_bits(float f) {
  __bf16 h = (__bf16)f;
  return *(unsigned short*)&h;
}
__device__ inline float bf2f(unsigned short u) {
  unsigned v = (unsigned)u << 16;
  return *(float*)&v;
}

// ---------------- router: fp32-exact logits, softmax, top-2 ----------------
// 128 blocks x 4 waves; each wave handles 8 tokens. Stats: per-wave register
// accumulation -> per-block LDS -> 25 global atomics/block (was 12 per token).
constexpr int RB = 128;
__global__ __launch_bounds__(256) void router_kernel(const float* __restrict__ x,
    const float* __restrict__ rw, int* __restrict__ meta,
    int* __restrict__ tke, float* __restrict__ gateArr) {
  __shared__ float s_imp[NE];
  __shared__ float s_z;
  __shared__ int s_cnt1[NE], s_cnta[NE];
  if (threadIdx.x < NE) { s_imp[threadIdx.x] = 0.f; s_cnt1[threadIdx.x] = 0; s_cnta[threadIdx.x] = 0; }
  if (threadIdx.x == 0) s_z = 0.f;
  __syncthreads();

  const int wave = threadIdx.x >> 6, lane = threadIdx.x & 63;
  float impacc[NE];
  #pragma unroll
  for (int e = 0; e < NE; ++e) impacc[e] = 0.f;
  float zacc = 0.f;

  for (int t = blockIdx.x * 4 + wave; t < NT; t += RB * 4) {
    float acc[NE];
    #pragma unroll
    for (int e = 0; e < NE; ++e) acc[e] = 0.f;
    const float* xr = x + (size_t)t * DD;
    for (int i = lane; i < DD; i += 64) {
      float xv = xr[i];
      const float* r = rw + i * NE;
      #pragma unroll
      for (int e = 0; e < NE; ++e) acc[e] += xv * r[e];
    }
    #pragma unroll
    for (int off = 32; off > 0; off >>= 1) {
      #pragma unroll
      for (int e = 0; e < NE; ++e) acc[e] += __shfl_xor(acc[e], off);
    }
    // softmax (all lanes redundantly)
    float mx = acc[0];
    #pragma unroll
    for (int e = 1; e < NE; ++e) mx = fmaxf(mx, acc[e]);
    float p[NE]; float s = 0.f;
    #pragma unroll
    for (int e = 0; e < NE; ++e) { p[e] = __expf(acc[e] - mx); s += p[e]; }
    float inv = 1.f / s;
    #pragma unroll
    for (int e = 0; e < NE; ++e) p[e] *= inv;
    // top-2, first-index-on-tie (matches jax.lax.top_k)
    int e0 = 0; float p0 = p[0];
    #pragma unroll
    for (int e = 1; e < NE; ++e) if (p[e] > p0) { p0 = p[e]; e0 = e; }
    int e1 = -1; float p1 = -1.f;
    #pragma unroll
    for (int e = 0; e < NE; ++e) if (e != e0 && p[e] > p1) { p1 = p[e]; e1 = e; }
    if (lane == 0) {
      #pragma unroll
      for (int e = 0; e < NE; ++e) { impacc[e] += p[e]; zacc += acc[e] * acc[e]; }
      atomicAdd(&s_cnt1[e0], 1);
      atomicAdd(&s_cnta[e0], 1);
      atomicAdd(&s_cnta[e1], 1);
      float gs = 1.f / (p0 + p1);
      tke[t*2]   = e0; tke[t*2+1] = e1;
      gateArr[t*2] = p0 * gs; gateArr[t*2+1] = p1 * gs;
    }
  }
  if (lane == 0) {
    #pragma unroll
    for (int e = 0; e < NE; ++e) atomicAdd(&s_imp[e], impacc[e]);
    atomicAdd(&s_z, zacc);
  }
  __syncthreads();
  float* fmeta = (float*)meta;
  if (threadIdx.x < NE) {
    atomicAdd(&fmeta[IDX_IMP + threadIdx.x], s_imp[threadIdx.x]);
    atomicAdd(&meta[IDX_CNTT1 + threadIdx.x], s_cnt1[threadIdx.x]);
    atomicAdd(&meta[IDX_CNTA + threadIdx.x], s_cnta[threadIdx.x]);
  }
  if (threadIdx.x == NE) atomicAdd(&fmeta[IDX_ZSUM], s_z);
}

// ---------------- scan: segment offsets + losses (1 thread, trivial work) --
__global__ void scan_kernel(int* __restrict__ meta, float* __restrict__ out_tail) {
  if (threadIdx.x != 0 || blockIdx.x != 0) return;
  float* fmeta = (float*)meta;
  int off = 0, tidx = 0;
  for (int e = 0; e < NE; ++e) {
    meta[IDX_OFF + e] = off;
    int ntile = (meta[IDX_CNTA + e] + 63) >> 6;
    for (int i = 0; i < ntile; ++i) meta[IDX_EXPT + tidx++] = e;
    off += ntile << 6;
  }
  meta[IDX_OFF + NE] = off;
  meta[IDX_NTILES] = tidx;
  float aux = 0.f;
  for (int e = 0; e < NE; ++e)
    aux += (fmeta[IDX_IMP + e] / (float)NT) * ((float)meta[IDX_CNTT1 + e] / (float)NT);
  out_tail[0] = (float)NE * aux * 0.01f;
  out_tail[1] = fmeta[IDX_ZSUM] / (float)(NT * NE) * 0.001f;
}

// ---------------- scatter: token -> padded row mapping --------------------
// Per-block LDS counting + one chunk-reservation global atomic per expert per
// block (16 blocks x 8 = 128 global atomics total, was 8192 on 8 addresses).
// Row order within a segment is arbitrary; gather/combine use the same map.
__global__ __launch_bounds__(256) void scatter_kernel(const int* __restrict__ tke,
    int* __restrict__ meta, int* __restrict__ rowof, int* __restrict__ tokrow) {
  __shared__ int s_cnt[NE], s_base[NE];
  const int t = blockIdx.x * 256 + threadIdx.x;
  if (threadIdx.x < NE) s_cnt[threadIdx.x] = 0;
  __syncthreads();
  const int e0 = tke[t*2], e1 = tke[t*2 + 1];
  const int l0 = atomicAdd(&s_cnt[e0], 1);
  const int l1 = atomicAdd(&s_cnt[e1], 1);
  __syncthreads();
  if (threadIdx.x < NE)
    s_base[threadIdx.x] = atomicAdd(&meta[IDX_CUR + threadIdx.x], s_cnt[threadIdx.x]);
  __syncthreads();
  const int r0 = meta[IDX_OFF + e0] + s_base[e0] + l0;
  const int r1 = meta[IDX_OFF + e1] + s_base[e1] + l1;
  rowof[t*2]     = r0;
  rowof[t*2 + 1] = r1;
  tokrow[r0] = t;
  tokrow[r1] = t;
}

// ---------------- gather x rows -> bf16 Xg (zeros for padding) ------------
__global__ __launch_bounds__(192) void gather_kernel(const float* __restrict__ x,
    const int* __restrict__ tokrow, const int* __restrict__ meta,
    __bf16* __restrict__ Xg) {
  const int row = blockIdx.x;
  if (row >= meta[IDX_OFF + NE]) return;
  const int tok = tokrow[row];
  ushort4* dst = (ushort4*)(Xg + (size_t)row * DD);
  const int i = threadIdx.x;            // 192 threads x 4 elems = 768
  ushort4 o;
  if (tok >= 0) {
    float4 v = ((const float4*)(x + (size_t)tok * DD))[i];
    o.x = f2bf_bits(v.x); o.y = f2bf_bits(v.y);
    o.z = f2bf_bits(v.z); o.w = f2bf_bits(v.w);
  } else {
    o.x = o.y = o.z = o.w = 0;
  }
  dst[i] = o;
}

// ---------------- transpose + fp32->bf16: [R][C] -> [C][R] ----------------
__global__ __launch_bounds__(256) void transpose_cvt(const float* __restrict__ src,
    __bf16* __restrict__ dst, int R, int C) {
  const size_t eoff = (size_t)blockIdx.z * R * C;
  src += eoff; dst += eoff;
  const int r0 = blockIdx.y * 64, c0 = blockIdx.x * 64;
  __shared__ __bf16 tile[64 * 65];
  const int t = threadIdx.x;
  #pragma unroll
  for (int i = 0; i < 16; ++i) {
    int idx = t + i * 256; int r = idx >> 6, c = idx & 63;
    tile[r * 65 + c] = (__bf16)src[(size_t)(r0 + r) * C + c0 + c];
  }
  __syncthreads();
  #pragma unroll
  for (int i = 0; i < 16; ++i) {
    int idx = t + i * 256; int c = idx >> 6, r = idx & 63;
    dst[(size_t)(c0 + c) * R + r0 + r] = tile[r * 65 + c];
  }
}

// ---------------- gemm1: H = silu(Xg@W1e) * (Xg@W3e) ----------------------
// tile 64Mx64N, K-step 32; A frag: A[m=lane&15][k=quad*8+j] (m120-verified)
__global__ __launch_bounds__(256) void gemm1_kernel(const __bf16* __restrict__ Xg,
    const __bf16* __restrict__ W1t, const __bf16* __restrict__ W3t,
    __bf16* __restrict__ Hb, const int* __restrict__ meta) {
  const int mt = blockIdx.y;
  if (mt >= meta[IDX_NTILES]) return;
  const int e = meta[IDX_EXPT + mt];
  const int n0 = blockIdx.x * 64;
  const int m0 = mt * 64;
  __shared__ __align__(16) __bf16 As[64*32], B1s[64*32], B3s[64*32];
  const int t = threadIdx.x, wave = t >> 6, lane = t & 63;
  const int sr = t >> 2, sc = (t & 3) * 8;  // staging: 16B per thread per tile
  const __bf16* w1e = W1t + (size_t)e * FF * DD;  // [FF][DD]
  const __bf16* w3e = W3t + (size_t)e * FF * DD;
  const f32x4 zero = {0.f, 0.f, 0.f, 0.f};
  f32x4 acc1[4] = {zero, zero, zero, zero};
  f32x4 acc3[4] = {zero, zero, zero, zero};
  for (int k0 = 0; k0 < DD; k0 += 32) {
    *(bf16x8v*)&As[sr*32 + sc]  = *(const bf16x8v*)&Xg [(size_t)(m0 + sr)*DD + k0 + sc];
    *(bf16x8v*)&B1s[sr*32 + sc] = *(const bf16x8v*)&w1e[(size_t)(n0 + sr)*DD + k0 + sc];
    *(bf16x8v*)&B3s[sr*32 + sc] = *(const bf16x8v*)&w3e[(size_t)(n0 + sr)*DD + k0 + sc];
    __syncthreads();
    bf16x8v a = *(const bf16x8v*)&As[(wave*16 + (lane & 15))*32 + (lane >> 4)*8];
    #pragma unroll
    for (int s = 0; s < 4; ++s) {
      bf16x8v b1 = *(const bf16x8v*)&B1s[(s*16 + (lane & 15))*32 + (lane >> 4)*8];
      bf16x8v b3 = *(const bf16x8v*)&B3s[(s*16 + (lane & 15))*32 + (lane >> 4)*8];
      acc1[s] = __builtin_amdgcn_mfma_f32_16x16x32_bf16(a, b1, acc1[s], 0, 0, 0);
      acc3[s] = __builtin_amdgcn_mfma_f32_16x16x32_bf16(a, b3, acc3[s], 0, 0, 0);
    }
    __syncthreads();
  }
  // C/D: row=(lane>>4)*4+r, col=lane&15 (m89-verified)
  const int rowb = m0 + wave*16 + (lane >> 4)*4;
  const int colb = n0 + (lane & 15);
  #pragma unroll
  for (int s = 0; s < 4; ++s) {
    #pragma unroll
    for (int r = 0; r < 4; ++r) {
      float c1 = acc1[s][r], c3 = acc3[s][r];
      float h = c1 / (1.f + __expf(-c1)) * c3;   // silu(c1)*c3
      Hb[(size_t)(rowb + r)*FF + colb + s*16] = (__bf16)h;
    }
  }
}

// ---------------- gemm2: OP = H @ W2e (bf16 partial) ----------------------
__global__ __launch_bounds__(256) void gemm2_kernel(const __bf16* __restrict__ Hb,
    const __bf16* __restrict__ W2t, __bf16* __restrict__ OP,
    const int* __restrict__ meta) {
  const int mt = blockIdx.y;
  if (mt >= meta[IDX_NTILES]) return;
  const int e = meta[IDX_EXPT + mt];
  const int n0 = blockIdx.x * 64;
  const int m0 = mt * 64;
  __shared__ __align__(16) __bf16 As[64*32], Bs[64*32];
  const int t = threadIdx.x, wave = t >> 6, lane = t & 63;
  const int sr = t >> 2, sc = (t & 3) * 8;
  const __bf16* w2e = W2t + (size_t)e * DD * FF;  // [DD][FF]
  const f32x4 zero = {0.f, 0.f, 0.f, 0.f};
  f32x4 acc[4] = {zero, zero, zero, zero};
  for (int k0 = 0; k0 < FF; k0 += 32) {
    *(bf16x8v*)&As[sr*32 + sc] = *(const bf16x8v*)&Hb [(size_t)(m0 + sr)*FF + k0 + sc];
    *(bf16x8v*)&Bs[sr*32 + sc] = *(const bf16x8v*)&w2e[(size_t)(n0 + sr)*FF + k0 + sc];
    __syncthreads();
    bf16x8v a = *(const bf16x8v*)&As[(wave*16 + (lane & 15))*32 + (lane >> 4)*8];
    #pragma unroll
    for (int s = 0; s < 4; ++s) {
      bf16x8v b = *(const bf16x8v*)&Bs[(s*16 + (lane & 15))*32 + (lane >> 4)*8];
      acc[s] = __builtin_amdgcn_mfma_f32_16x16x32_bf16(a, b, acc[s], 0, 0, 0);
    }
    __syncthreads();
  }
  const int rowb = m0 + wave*16 + (lane >> 4)*4;
  const int colb = n0 + (lane & 15);
  #pragma unroll
  for (int s = 0; s < 4; ++s) {
    #pragma unroll
    for (int r = 0; r < 4; ++r)
      OP[(size_t)(rowb + r)*DD + colb + s*16] = (__bf16)acc[s][r];
  }
}

// ---------------- combine: out[t] = g0*OP[row0] + g1*OP[row1] -------------
__global__ __launch_bounds__(192) void combine_kernel(const __bf16* __restrict__ OP,
    const int* __restrict__ rowof, const float* __restrict__ gateArr,
    float* __restrict__ out) {
  const int t = blockIdx.x;
  const int r0 = rowof[t*2], r1 = rowof[t*2 + 1];
  const float g0 = gateArr[t*2], g1 = gateArr[t*2 + 1];
  const ushort4* p0 = (const ushort4*)(OP + (size_t)r0 * DD);
  const ushort4* p1 = (const ushort4*)(OP + (size_t)r1 * DD);
  const int i = threadIdx.x;            // 192 threads x 4 elems = 768
  ushort4 a = p0[i], b = p1[i];
  float4 o;
  o.x = g0 * bf2f(a.x) + g1 * bf2f(b.x);
  o.y = g0 * bf2f(a.y) + g1 * bf2f(b.y);
  o.z = g0 * bf2f(a.z) + g1 * bf2f(b.z);
  o.w = g0 * bf2f(a.w) + g1 * bf2f(b.w);
  ((float4*)(out + (size_t)t * DD))[i] = o;
}

extern "C" void kernel_launch(void* const* d_in, const int* in_sizes, int n_in,
                              void* d_out, int out_size, void* d_ws, size_t ws_size,
                              hipStream_t stream) {
  const float* x  = (const float*)d_in[0];
  const float* rw = (const float*)d_in[1];
  const float* w1 = (const float*)d_in[2];
  const float* w2 = (const float*)d_in[3];
  const float* w3 = (const float*)d_in[4];
  float* out = (float*)d_out;

  char* ws = (char*)d_ws;
  int*    meta   = (int*)(ws + OFF_META);
  int*    tke    = (int*)(ws + OFF_TKE);
  float*  gateA  = (float*)(ws + OFF_GATE);
  int*    rowof  = (int*)(ws + OFF_ROWOF);
  int*    tokrow = (int*)(ws + OFF_TOKROW);
  __bf16* Xg     = (__bf16*)(ws + OFF_XG);
  __bf16* W1t    = (__bf16*)(ws + OFF_W1T);
  __bf16* W3t    = (__bf16*)(ws + OFF_W3T);
  __bf16* W2t    = (__bf16*)(ws + OFF_W2T);
  __bf16* Hb     = (__bf16*)(ws + OFF_H);
  __bf16* OP     = (__bf16*)(ws + OFF_OP);

  hipMemsetAsync(ws + OFF_META, 0, 1024, stream);
  hipMemsetAsync(ws + OFF_TOKROW, 0xFF, (size_t)MAXROWS * 4, stream);  // tok=-1

  // weights -> bf16, K-contiguous ([N][K]) for MFMA B-fragments
  transpose_cvt<<<dim3(FF/64, DD/64, NE), 256, 0, stream>>>(w1, W1t, DD, FF);
  transpose_cvt<<<dim3(FF/64, DD/64, NE), 256, 0, stream>>>(w3, W3t, DD, FF);
  transpose_cvt<<<dim3(DD/64, FF/64, NE), 256, 0, stream>>>(w2, W2t, FF, DD);

  router_kernel<<<RB, 256, 0, stream>>>(x, rw, meta, tke, gateA);
  scan_kernel<<<1, 64, 0, stream>>>(meta, out + (size_t)NT * DD);
  scatter_kernel<<<NT/256, 256, 0, stream>>>(tke, meta, rowof, tokrow);
  gather_kernel<<<MAXROWS, 192, 0, stream>>>(x, tokrow, meta, Xg);

  gemm1_kernel<<<dim3(FF/64, MAXTILES), 256, 0, stream>>>(Xg, W1t, W3t, Hb, meta);
  gemm2_kernel<<<dim3(DD/64, MAXTILES), 256, 0, stream>>>(Hb, W2t, OP, meta);
  combine_kernel<<<NT, 192, 0, stream>>>(OP, rowof, gateA, out);
}

// Round 3
// 382.056 us; speedup vs baseline: 2.2158x; 1.1207x over previous
//
#include <hip/hip_runtime.h>
#include <hip/hip_bf16.h>

// ---------------- problem constants (fixed by reference) ----------------
constexpr int NT = 4096;   // tokens = B*S = 2*2048
constexpr int DD = 768;    // model dim
constexpr int FF = 2048;   // ffn dim
constexpr int NE = 8;      // experts
constexpr int MAXROWS = 9216;   // 8192 + 8*127 rounded up to 128
constexpr int MAXMT128 = 72;    // MAXROWS/128

// meta layout (int indices into ws[0..1024))
constexpr int IDX_CNTA   = 0;   // [8]  assignments per expert
constexpr int IDX_CNTT1  = 8;   // [8]  top-1 counts (load)
constexpr int IDX_CUR    = 16;  // [8]  scatter cursors
constexpr int IDX_IMP    = 24;  // [8]  float: sum of probs per expert
constexpr int IDX_ZSUM   = 32;  // float: sum logits^2
constexpr int IDX_NTILES = 33;
constexpr int IDX_OFF    = 34;  // [9]  128-aligned segment offsets
constexpr int IDX_EXPT   = 48;  // [MAXMT128] tile -> expert

// ws byte offsets (all 256-aligned)
constexpr size_t OFF_META   = 0;
constexpr size_t OFF_TKE    = 1024;                         // int [NT][2]
constexpr size_t OFF_GATE   = OFF_TKE    + (size_t)NT*2*4;  // float [NT][2]
constexpr size_t OFF_ROWOF  = OFF_GATE   + (size_t)NT*2*4;  // int [NT][2]
constexpr size_t OFF_TOKROW = OFF_ROWOF  + (size_t)NT*2*4;  // int [MAXROWS]
constexpr size_t OFF_XG     = 136448;                              // bf16 [MAXROWS][DD]
constexpr size_t OFF_W1T    = OFF_XG  + (size_t)MAXROWS*DD*2;      // bf16 [NE][FF][DD]
constexpr size_t OFF_W3T    = OFF_W1T + (size_t)NE*FF*DD*2;
constexpr size_t OFF_W2T    = OFF_W3T + (size_t)NE*FF*DD*2;        // bf16 [NE][DD][FF]
constexpr size_t OFF_H      = OFF_W2T + (size_t)NE*FF*DD*2;        // bf16 [MAXROWS][FF]
constexpr size_t OFF_OP     = OFF_H   + (size_t)MAXROWS*FF*2;      // bf16 [MAXROWS][DD]

typedef float f32x4 __attribute__((ext_vector_type(4)));
typedef __bf16 bf16x8v __attribute__((ext_vector_type(8)));

__device__ inline unsigned short f2bf_bits(float f) {
  __bf16 h = (__bf16)f;
  return *(unsigned short*)&h;
}
__device__ inline float bf2f(unsigned short u) {
  unsigned v = (unsigned)u << 16;
  return *(float*)&v;
}

// async 16B global->LDS; LDS dest = wave-uniform base + lane*16 (m97/m104)
__device__ __forceinline__ void glds16(const void* g, void* l) {
  __builtin_amdgcn_global_load_lds(
      (const __attribute__((address_space(1))) unsigned int*)g,
      (__attribute__((address_space(3))) unsigned int*)l, 16, 0, 0);
}

// ---------------- router: fp32-exact logits, softmax, top-2 ----------------
constexpr int RB = 128;
__global__ __launch_bounds__(256) void router_kernel(const float* __restrict__ x,
    const float* __restrict__ rw, int* __restrict__ meta,
    int* __restrict__ tke, float* __restrict__ gateArr) {
  __shared__ float s_imp[NE];
  __shared__ float s_z;
  __shared__ int s_cnt1[NE], s_cnta[NE];
  if (threadIdx.x < NE) { s_imp[threadIdx.x] = 0.f; s_cnt1[threadIdx.x] = 0; s_cnta[threadIdx.x] = 0; }
  if (threadIdx.x == 0) s_z = 0.f;
  __syncthreads();

  const int wave = threadIdx.x >> 6, lane = threadIdx.x & 63;
  float impacc[NE];
  #pragma unroll
  for (int e = 0; e < NE; ++e) impacc[e] = 0.f;
  float zacc = 0.f;

  for (int t = blockIdx.x * 4 + wave; t < NT; t += RB * 4) {
    float acc[NE];
    #pragma unroll
    for (int e = 0; e < NE; ++e) acc[e] = 0.f;
    const float* xr = x + (size_t)t * DD;
    for (int i = lane; i < DD; i += 64) {
      float xv = xr[i];
      const float* r = rw + i * NE;
      #pragma unroll
      for (int e = 0; e < NE; ++e) acc[e] += xv * r[e];
    }
    #pragma unroll
    for (int off = 32; off > 0; off >>= 1) {
      #pragma unroll
      for (int e = 0; e < NE; ++e) acc[e] += __shfl_xor(acc[e], off);
    }
    float mx = acc[0];
    #pragma unroll
    for (int e = 1; e < NE; ++e) mx = fmaxf(mx, acc[e]);
    float p[NE]; float s = 0.f;
    #pragma unroll
    for (int e = 0; e < NE; ++e) { p[e] = __expf(acc[e] - mx); s += p[e]; }
    float inv = 1.f / s;
    #pragma unroll
    for (int e = 0; e < NE; ++e) p[e] *= inv;
    int e0 = 0; float p0 = p[0];
    #pragma unroll
    for (int e = 1; e < NE; ++e) if (p[e] > p0) { p0 = p[e]; e0 = e; }
    int e1 = -1; float p1 = -1.f;
    #pragma unroll
    for (int e = 0; e < NE; ++e) if (e != e0 && p[e] > p1) { p1 = p[e]; e1 = e; }
    if (lane == 0) {
      #pragma unroll
      for (int e = 0; e < NE; ++e) { impacc[e] += p[e]; zacc += acc[e] * acc[e]; }
      atomicAdd(&s_cnt1[e0], 1);
      atomicAdd(&s_cnta[e0], 1);
      atomicAdd(&s_cnta[e1], 1);
      float gs = 1.f / (p0 + p1);
      tke[t*2]   = e0; tke[t*2+1] = e1;
      gateArr[t*2] = p0 * gs; gateArr[t*2+1] = p1 * gs;
    }
  }
  if (lane == 0) {
    #pragma unroll
    for (int e = 0; e < NE; ++e) atomicAdd(&s_imp[e], impacc[e]);
    atomicAdd(&s_z, zacc);
  }
  __syncthreads();
  float* fmeta = (float*)meta;
  if (threadIdx.x < NE) {
    atomicAdd(&fmeta[IDX_IMP + threadIdx.x], s_imp[threadIdx.x]);
    atomicAdd(&meta[IDX_CNTT1 + threadIdx.x], s_cnt1[threadIdx.x]);
    atomicAdd(&meta[IDX_CNTA + threadIdx.x], s_cnta[threadIdx.x]);
  }
  if (threadIdx.x == NE) atomicAdd(&fmeta[IDX_ZSUM], s_z);
}

// ---------------- scan: 128-aligned segment offsets + losses --------------
__global__ void scan_kernel(int* __restrict__ meta, float* __restrict__ out_tail) {
  if (threadIdx.x != 0 || blockIdx.x != 0) return;
  float* fmeta = (float*)meta;
  int off = 0, tidx = 0;
  for (int e = 0; e < NE; ++e) {
    meta[IDX_OFF + e] = off;
    int ntile = (meta[IDX_CNTA + e] + 127) >> 7;
    for (int i = 0; i < ntile; ++i) meta[IDX_EXPT + tidx++] = e;
    off += ntile << 7;
  }
  meta[IDX_OFF + NE] = off;
  meta[IDX_NTILES] = tidx;
  float aux = 0.f;
  for (int e = 0; e < NE; ++e)
    aux += (fmeta[IDX_IMP + e] / (float)NT) * ((float)meta[IDX_CNTT1 + e] / (float)NT);
  out_tail[0] = (float)NE * aux * 0.01f;
  out_tail[1] = fmeta[IDX_ZSUM] / (float)(NT * NE) * 0.001f;
}

// ---------------- scatter: block-chunked cursor reservation ---------------
__global__ __launch_bounds__(256) void scatter_kernel(const int* __restrict__ tke,
    int* __restrict__ meta, int* __restrict__ rowof, int* __restrict__ tokrow) {
  __shared__ int s_cnt[NE], s_base[NE];
  const int t = blockIdx.x * 256 + threadIdx.x;
  if (threadIdx.x < NE) s_cnt[threadIdx.x] = 0;
  __syncthreads();
  const int e0 = tke[t*2], e1 = tke[t*2 + 1];
  const int l0 = atomicAdd(&s_cnt[e0], 1);
  const int l1 = atomicAdd(&s_cnt[e1], 1);
  __syncthreads();
  if (threadIdx.x < NE)
    s_base[threadIdx.x] = atomicAdd(&meta[IDX_CUR + threadIdx.x], s_cnt[threadIdx.x]);
  __syncthreads();
  const int r0 = meta[IDX_OFF + e0] + s_base[e0] + l0;
  const int r1 = meta[IDX_OFF + e1] + s_base[e1] + l1;
  rowof[t*2]     = r0;
  rowof[t*2 + 1] = r1;
  tokrow[r0] = t;
  tokrow[r1] = t;
}

// ---------------- gather x rows -> bf16 Xg (zeros for padding) ------------
__global__ __launch_bounds__(192) void gather_kernel(const float* __restrict__ x,
    const int* __restrict__ tokrow, const int* __restrict__ meta,
    __bf16* __restrict__ Xg) {
  const int row = blockIdx.x;
  if (row >= meta[IDX_OFF + NE]) return;
  const int tok = tokrow[row];
  ushort4* dst = (ushort4*)(Xg + (size_t)row * DD);
  const int i = threadIdx.x;            // 192 threads x 4 elems = 768
  ushort4 o;
  if (tok >= 0) {
    float4 v = ((const float4*)(x + (size_t)tok * DD))[i];
    o.x = f2bf_bits(v.x); o.y = f2bf_bits(v.y);
    o.z = f2bf_bits(v.z); o.w = f2bf_bits(v.w);
  } else {
    o.x = o.y = o.z = o.w = 0;
  }
  dst[i] = o;
}

// ------------- one-shot transpose + fp32->bf16 for all 3 weights ----------
// z = which*8 + e. w1/w3: [DD][FF] -> [FF][DD]; w2: [FF][DD] -> [DD][FF].
__global__ __launch_bounds__(256) void transpose_cvt_all(
    const float* __restrict__ w1, const float* __restrict__ w3,
    const float* __restrict__ w2, __bf16* __restrict__ W1t,
    __bf16* __restrict__ W3t, __bf16* __restrict__ W2t) {
  const int z = blockIdx.z, which = z >> 3, e = z & 7;
  const float* src; __bf16* dst; int R, C, rt, ct;
  if (which == 0)      { src = w1; dst = W1t; R = DD; C = FF; rt = blockIdx.y; ct = blockIdx.x; }
  else if (which == 1) { src = w3; dst = W3t; R = DD; C = FF; rt = blockIdx.y; ct = blockIdx.x; }
  else                 { src = w2; dst = W2t; R = FF; C = DD; rt = blockIdx.x; ct = blockIdx.y; }
  src += (size_t)e * DD * FF; dst += (size_t)e * DD * FF;
  const int r0 = rt * 64, c0 = ct * 64;
  __shared__ __bf16 tile[64 * 65];
  const int t = threadIdx.x;
  #pragma unroll
  for (int i = 0; i < 16; ++i) {
    int idx = t + i * 256; int r = idx >> 6, c = idx & 63;
    tile[r * 65 + c] = (__bf16)src[(size_t)(r0 + r) * C + c0 + c];
  }
  __syncthreads();
  #pragma unroll
  for (int i = 0; i < 8; ++i) {      // 2048 ushort2 stores = 64x64
    int idx = t + i * 256; int c = idx >> 5, rp = idx & 31;
    ushort2 o;
    o.x = *(unsigned short*)&tile[(rp*2    ) * 65 + c];
    o.y = *(unsigned short*)&tile[(rp*2 + 1) * 65 + c];
    *(ushort2*)&dst[(size_t)(c0 + c) * R + r0 + rp*2] = o;
  }
}

// ---------------- gemm1: H = silu(Xg@W1e) * (Xg@W3e) ----------------------
// 128M x 64N dual-B tile, async global->LDS staging (m97 pattern).
// wave w: rows [32w,32w+32), all 64 cols; acc 2x4 per B matrix.
__global__ __launch_bounds__(256) void gemm1_kernel(const __bf16* __restrict__ Xg,
    const __bf16* __restrict__ W1t, const __bf16* __restrict__ W3t,
    __bf16* __restrict__ Hb, const int* __restrict__ meta) {
  const int mt = blockIdx.y;
  if (mt >= meta[IDX_NTILES]) return;
  const int e = meta[IDX_EXPT + mt];
  const int n0 = blockIdx.x * 64;
  const int m0 = mt * 128;
  __shared__ __align__(16) __bf16 As[128*32], B1s[64*32], B3s[64*32];
  const int t = threadIdx.x, wave = t >> 6, lane = t & 63;
  const __bf16* w1e = W1t + (size_t)e * FF * DD;  // [FF][DD]
  const __bf16* w3e = W3t + (size_t)e * FF * DD;
  const f32x4 zero = {0.f, 0.f, 0.f, 0.f};
  f32x4 acc1[2][4], acc3[2][4];
  #pragma unroll
  for (int i = 0; i < 2; ++i)
    #pragma unroll
    for (int j = 0; j < 4; ++j) { acc1[i][j] = zero; acc3[i][j] = zero; }

  // per-lane global source offsets (16B each)
  const __bf16* gA  = Xg  + (size_t)(m0 + 32*wave + (lane >> 2)) * DD + (lane & 3) * 8;
  const __bf16* gB1 = w1e + (size_t)(n0 + 16*wave + (lane >> 2)) * DD + (lane & 3) * 8;
  const __bf16* gB3 = w3e + (size_t)(n0 + 16*wave + (lane >> 2)) * DD + (lane & 3) * 8;
  __bf16* lA0 = &As [(32*wave     ) * 32];
  __bf16* lA1 = &As [(32*wave + 16) * 32];
  __bf16* lB1 = &B1s[(16*wave     ) * 32];
  __bf16* lB3 = &B3s[(16*wave     ) * 32];

  for (int k0 = 0; k0 < DD; k0 += 32) {
    glds16(gA  + k0,           lA0);
    glds16(gA  + k0 + 16*DD,   lA1);
    glds16(gB1 + k0,           lB1);
    glds16(gB3 + k0,           lB3);
    __syncthreads();
    bf16x8v a[2], b1[4], b3[4];
    #pragma unroll
    for (int i = 0; i < 2; ++i)
      a[i] = *(const bf16x8v*)&As[(32*wave + 16*i + (lane & 15))*32 + (lane >> 4)*8];
    #pragma unroll
    for (int j = 0; j < 4; ++j) {
      b1[j] = *(const bf16x8v*)&B1s[(16*j + (lane & 15))*32 + (lane >> 4)*8];
      b3[j] = *(const bf16x8v*)&B3s[(16*j + (lane & 15))*32 + (lane >> 4)*8];
    }
    #pragma unroll
    for (int i = 0; i < 2; ++i)
      #pragma unroll
      for (int j = 0; j < 4; ++j) {
        acc1[i][j] = __builtin_amdgcn_mfma_f32_16x16x32_bf16(a[i], b1[j], acc1[i][j], 0, 0, 0);
        acc3[i][j] = __builtin_amdgcn_mfma_f32_16x16x32_bf16(a[i], b3[j], acc3[i][j], 0, 0, 0);
      }
    __syncthreads();
  }
  // C/D: row=(lane>>4)*4+r, col=lane&15 (m89-verified)
  #pragma unroll
  for (int i = 0; i < 2; ++i) {
    const int rowb = m0 + 32*wave + 16*i + (lane >> 4)*4;
    #pragma unroll
    for (int j = 0; j < 4; ++j) {
      const int col = n0 + 16*j + (lane & 15);
      #pragma unroll
      for (int r = 0; r < 4; ++r) {
        float c1 = acc1[i][j][r], c3 = acc3[i][j][r];
        float h = c1 / (1.f + __expf(-c1)) * c3;   // silu(c1)*c3
        Hb[(size_t)(rowb + r)*FF + col] = (__bf16)h;
      }
    }
  }
}

// ---------------- gemm2: OP = H @ W2e; 128x128 m97-style ------------------
__global__ __launch_bounds__(256) void gemm2_kernel(const __bf16* __restrict__ Hb,
    const __bf16* __restrict__ W2t, __bf16* __restrict__ OP,
    const int* __restrict__ meta) {
  const int mt = blockIdx.y;
  if (mt >= meta[IDX_NTILES]) return;
  const int e = meta[IDX_EXPT + mt];
  const int n0 = blockIdx.x * 128;
  const int m0 = mt * 128;
  __shared__ __align__(16) __bf16 As[128*32], Bs[128*32];
  const int t = threadIdx.x, wave = t >> 6, lane = t & 63;
  const int wm = wave & 1, wn = wave >> 1;
  const __bf16* w2e = W2t + (size_t)e * DD * FF;  // [DD][FF]
  const f32x4 zero = {0.f, 0.f, 0.f, 0.f};
  f32x4 acc[4][4];
  #pragma unroll
  for (int i = 0; i < 4; ++i)
    #pragma unroll
    for (int j = 0; j < 4; ++j) acc[i][j] = zero;

  const __bf16* gA = Hb  + (size_t)(m0 + 32*wave + (lane >> 2)) * FF + (lane & 3) * 8;
  const __bf16* gB = w2e + (size_t)(n0 + 32*wave + (lane >> 2)) * FF + (lane & 3) * 8;
  __bf16* lA0 = &As[(32*wave     ) * 32];
  __bf16* lA1 = &As[(32*wave + 16) * 32];
  __bf16* lB0 = &Bs[(32*wave     ) * 32];
  __bf16* lB1 = &Bs[(32*wave + 16) * 32];

  for (int k0 = 0; k0 < FF; k0 += 32) {
    glds16(gA + k0,          lA0);
    glds16(gA + k0 + 16*FF,  lA1);
    glds16(gB + k0,          lB0);
    glds16(gB + k0 + 16*FF,  lB1);
    __syncthreads();
    bf16x8v a[4], b[4];
    #pragma unroll
    for (int i = 0; i < 4; ++i) {
      a[i] = *(const bf16x8v*)&As[(64*wm + 16*i + (lane & 15))*32 + (lane >> 4)*8];
      b[i] = *(const bf16x8v*)&Bs[(64*wn + 16*i + (lane & 15))*32 + (lane >> 4)*8];
    }
    #pragma unroll
    for (int i = 0; i < 4; ++i)
      #pragma unroll
      for (int j = 0; j < 4; ++j)
        acc[i][j] = __builtin_amdgcn_mfma_f32_16x16x32_bf16(a[i], b[j], acc[i][j], 0, 0, 0);
    __syncthreads();
  }
  #pragma unroll
  for (int i = 0; i < 4; ++i) {
    const int rowb = m0 + 64*wm + 16*i + (lane >> 4)*4;
    #pragma unroll
    for (int j = 0; j < 4; ++j) {
      const int col = n0 + 64*wn + 16*j + (lane & 15);
      #pragma unroll
      for (int r = 0; r < 4; ++r)
        OP[(size_t)(rowb + r)*DD + col] = (__bf16)acc[i][j][r];
    }
  }
}

// ---------------- combine: out[t] = g0*OP[row0] + g1*OP[row1] -------------
__global__ __launch_bounds__(192) void combine_kernel(const __bf16* __restrict__ OP,
    const int* __restrict__ rowof, const float* __restrict__ gateArr,
    float* __restrict__ out) {
  const int t = blockIdx.x;
  const int r0 = rowof[t*2], r1 = rowof[t*2 + 1];
  const float g0 = gateArr[t*2], g1 = gateArr[t*2 + 1];
  const ushort4* p0 = (const ushort4*)(OP + (size_t)r0 * DD);
  const ushort4* p1 = (const ushort4*)(OP + (size_t)r1 * DD);
  const int i = threadIdx.x;
  ushort4 a = p0[i], b = p1[i];
  float4 o;
  o.x = g0 * bf2f(a.x) + g1 * bf2f(b.x);
  o.y = g0 * bf2f(a.y) + g1 * bf2f(b.y);
  o.z = g0 * bf2f(a.z) + g1 * bf2f(b.z);
  o.w = g0 * bf2f(a.w) + g1 * bf2f(b.w);
  ((float4*)(out + (size_t)t * DD))[i] = o;
}

extern "C" void kernel_launch(void* const* d_in, const int* in_sizes, int n_in,
                              void* d_out, int out_size, void* d_ws, size_t ws_size,
                              hipStream_t stream) {
  const float* x  = (const float*)d_in[0];
  const float* rw = (const float*)d_in[1];
  const float* w1 = (const float*)d_in[2];
  const float* w2 = (const float*)d_in[3];
  const float* w3 = (const float*)d_in[4];
  float* out = (float*)d_out;

  char* ws = (char*)d_ws;
  int*    meta   = (int*)(ws + OFF_META);
  int*    tke    = (int*)(ws + OFF_TKE);
  float*  gateA  = (float*)(ws + OFF_GATE);
  int*    rowof  = (int*)(ws + OFF_ROWOF);
  int*    tokrow = (int*)(ws + OFF_TOKROW);
  __bf16* Xg     = (__bf16*)(ws + OFF_XG);
  __bf16* W1t    = (__bf16*)(ws + OFF_W1T);
  __bf16* W3t    = (__bf16*)(ws + OFF_W3T);
  __bf16* W2t    = (__bf16*)(ws + OFF_W2T);
  __bf16* Hb     = (__bf16*)(ws + OFF_H);
  __bf16* OP     = (__bf16*)(ws + OFF_OP);

  hipMemsetAsync(ws + OFF_META, 0, 1024, stream);
  hipMemsetAsync(ws + OFF_TOKROW, 0xFF, (size_t)MAXROWS * 4, stream);  // tok=-1

  transpose_cvt_all<<<dim3(32, 12, 24), 256, 0, stream>>>(w1, w3, w2, W1t, W3t, W2t);

  router_kernel<<<RB, 256, 0, stream>>>(x, rw, meta, tke, gateA);
  scan_kernel<<<1, 64, 0, stream>>>(meta, out + (size_t)NT * DD);
  scatter_kernel<<<NT/256, 256, 0, stream>>>(tke, meta, rowof, tokrow);
  gather_kernel<<<MAXROWS, 192, 0, stream>>>(x, tokrow, meta, Xg);

  gemm1_kernel<<<dim3(FF/64, MAXMT128), 256, 0, stream>>>(Xg, W1t, W3t, Hb, meta);
  gemm2_kernel<<<dim3(DD/128, MAXMT128), 256, 0, stream>>>(Hb, W2t, OP, meta);
  combine_kernel<<<NT, 192, 0, stream>>>(OP, rowof, gateA, out);
}

// Round 5
// 377.995 us; speedup vs baseline: 2.2396x; 1.0107x over previous
//
#include <hip/hip_runtime.h>
#include <hip/hip_bf16.h>

// ---------------- problem constants (fixed by reference) ----------------
constexpr int NT = 4096;   // tokens = B*S = 2*2048
constexpr int DD = 768;    // model dim
constexpr int FF = 2048;   // ffn dim
constexpr int NE = 8;      // experts
constexpr int MAXROWS = 9216;   // 8192 + 8*127 rounded up to 128
constexpr int MAXMT128 = 72;    // MAXROWS/128

// meta layout (int indices into ws[0..1024))
constexpr int IDX_CNTA   = 0;   // [8]  assignments per expert
constexpr int IDX_CNTT1  = 8;   // [8]  top-1 counts (load)
constexpr int IDX_CUR    = 16;  // [8]  scatter cursors
constexpr int IDX_IMP    = 24;  // [8]  float: sum of probs per expert
constexpr int IDX_ZSUM   = 32;  // float: sum logits^2
constexpr int IDX_NTILES = 33;
constexpr int IDX_OFF    = 34;  // [9]  128-aligned segment offsets
constexpr int IDX_EXPT   = 48;  // [MAXMT128] tile -> expert

// ws byte offsets (all 256-aligned)
constexpr size_t OFF_META   = 0;
constexpr size_t OFF_TKE    = 1024;                           // int [NT][2]
constexpr size_t OFF_GATE   = OFF_TKE    + (size_t)NT*2*4;    // float [NT][2]
constexpr size_t OFF_ROWOF  = OFF_GATE   + (size_t)NT*2*4;    // int [NT][2]
constexpr size_t OFF_TOKROW = OFF_ROWOF  + (size_t)NT*2*4;    // int [MAXROWS]
constexpr size_t OFF_XG     = 136192;                              // bf16 [MAXROWS][DD]
constexpr size_t OFF_W1T    = OFF_XG  + (size_t)MAXROWS*DD*2;      // bf16 [NE][FF][DD]
constexpr size_t OFF_W3T    = OFF_W1T + (size_t)NE*FF*DD*2;
constexpr size_t OFF_W2T    = OFF_W3T + (size_t)NE*FF*DD*2;        // bf16 [NE][DD][FF]
constexpr size_t OFF_H      = OFF_W2T + (size_t)NE*FF*DD*2;        // bf16 [MAXROWS][FF]
constexpr size_t OFF_OP     = OFF_H   + (size_t)MAXROWS*FF*2;      // bf16 [MAXROWS][DD]

typedef float f32x4 __attribute__((ext_vector_type(4)));
typedef __bf16 bf16x8v __attribute__((ext_vector_type(8)));
typedef unsigned short u16x8 __attribute__((ext_vector_type(8)));

__device__ inline unsigned short f2bf_bits(float f) {
  __bf16 h = (__bf16)f;
  return *(unsigned short*)&h;
}
__device__ inline float bf2f(unsigned short u) {
  unsigned v = (unsigned)u << 16;
  return *(float*)&v;
}

// async 16B global->LDS; LDS dest = wave-uniform base + lane*16 (m97/m104)
__device__ __forceinline__ void glds16(const void* g, void* l) {
  __builtin_amdgcn_global_load_lds(
      (const __attribute__((address_space(1))) unsigned int*)g,
      (__attribute__((address_space(3))) unsigned int*)l, 16, 0, 0);
}

// ---------------- router: fp32-exact logits, softmax, top-2 ----------------
constexpr int RB = 128;
__global__ __launch_bounds__(256) void router_kernel(const float* __restrict__ x,
    const float* __restrict__ rw, int* __restrict__ meta,
    int* __restrict__ tke, float* __restrict__ gateArr) {
  __shared__ float s_imp[NE];
  __shared__ float s_z;
  __shared__ int s_cnt1[NE], s_cnta[NE];
  if (threadIdx.x < NE) { s_imp[threadIdx.x] = 0.f; s_cnt1[threadIdx.x] = 0; s_cnta[threadIdx.x] = 0; }
  if (threadIdx.x == 0) s_z = 0.f;
  __syncthreads();

  const int wave = threadIdx.x >> 6, lane = threadIdx.x & 63;
  float impacc[NE];
  #pragma unroll
  for (int e = 0; e < NE; ++e) impacc[e] = 0.f;
  float zacc = 0.f;

  for (int t = blockIdx.x * 4 + wave; t < NT; t += RB * 4) {
    float acc[NE];
    #pragma unroll
    for (int e = 0; e < NE; ++e) acc[e] = 0.f;
    const float* xr = x + (size_t)t * DD;
    for (int i = lane; i < DD; i += 64) {
      float xv = xr[i];
      const float* r = rw + i * NE;
      #pragma unroll
      for (int e = 0; e < NE; ++e) acc[e] += xv * r[e];
    }
    #pragma unroll
    for (int off = 32; off > 0; off >>= 1) {
      #pragma unroll
      for (int e = 0; e < NE; ++e) acc[e] += __shfl_xor(acc[e], off);
    }
    float mx = acc[0];
    #pragma unroll
    for (int e = 1; e < NE; ++e) mx = fmaxf(mx, acc[e]);
    float p[NE]; float s = 0.f;
    #pragma unroll
    for (int e = 0; e < NE; ++e) { p[e] = __expf(acc[e] - mx); s += p[e]; }
    float inv = 1.f / s;
    #pragma unroll
    for (int e = 0; e < NE; ++e) p[e] *= inv;
    int e0 = 0; float p0 = p[0];
    #pragma unroll
    for (int e = 1; e < NE; ++e) if (p[e] > p0) { p0 = p[e]; e0 = e; }
    int e1 = -1; float p1 = -1.f;
    #pragma unroll
    for (int e = 0; e < NE; ++e) if (e != e0 && p[e] > p1) { p1 = p[e]; e1 = e; }
    if (lane == 0) {
      #pragma unroll
      for (int e = 0; e < NE; ++e) { impacc[e] += p[e]; zacc += acc[e] * acc[e]; }
      atomicAdd(&s_cnt1[e0], 1);
      atomicAdd(&s_cnta[e0], 1);
      atomicAdd(&s_cnta[e1], 1);
      float gs = 1.f / (p0 + p1);
      tke[t*2]   = e0; tke[t*2+1] = e1;
      gateArr[t*2] = p0 * gs; gateArr[t*2+1] = p1 * gs;
    }
  }
  if (lane == 0) {
    #pragma unroll
    for (int e = 0; e < NE; ++e) atomicAdd(&s_imp[e], impacc[e]);
    atomicAdd(&s_z, zacc);
  }
  __syncthreads();
  float* fmeta = (float*)meta;
  if (threadIdx.x < NE) {
    atomicAdd(&fmeta[IDX_IMP + threadIdx.x], s_imp[threadIdx.x]);
    atomicAdd(&meta[IDX_CNTT1 + threadIdx.x], s_cnt1[threadIdx.x]);
    atomicAdd(&meta[IDX_CNTA + threadIdx.x], s_cnta[threadIdx.x]);
  }
  if (threadIdx.x == NE) atomicAdd(&fmeta[IDX_ZSUM], s_z);
}

// ------------ scan (parallel): segment offsets + losses -------------------
__global__ __launch_bounds__(128) void scan_kernel(int* __restrict__ meta,
                                                   float* __restrict__ out_tail) {
  __shared__ int s_off[NE + 1];
  __shared__ int s_nt[NE];
  __shared__ float s_aux;
  const int t = threadIdx.x;
  if (t < NE) s_nt[t] = (meta[IDX_CNTA + t] + 127) >> 7;
  __syncthreads();
  if (t == 0) {
    int off = 0;
    for (int e = 0; e < NE; ++e) { s_off[e] = off; off += s_nt[e]; }
    s_off[NE] = off;
  }
  __syncthreads();
  const int ntiles = s_off[NE];
  if (t < NE) meta[IDX_OFF + t] = s_off[t] << 7;
  if (t == NE) { meta[IDX_OFF + NE] = ntiles << 7; meta[IDX_NTILES] = ntiles; }
  if (t < ntiles) {
    int e = 0;
    while (t >= s_off[e + 1]) e++;
    meta[IDX_EXPT + t] = e;
  }
  float* fmeta = (float*)meta;
  float pl = 0.f;
  if (t < NE)
    pl = (fmeta[IDX_IMP + t] / (float)NT) * ((float)meta[IDX_CNTT1 + t] / (float)NT);
  if (t < 64) {
    #pragma unroll
    for (int off = 4; off > 0; off >>= 1) pl += __shfl_xor(pl, off);
    if (t == 0) s_aux = pl;
  }
  __syncthreads();
  if (t == 0) {
    out_tail[0] = (float)NE * s_aux * 0.01f;
    out_tail[1] = fmeta[IDX_ZSUM] / (float)(NT * NE) * 0.001f;
  }
}

// ---------------- scatter: block-chunked cursor reservation ---------------
__global__ __launch_bounds__(256) void scatter_kernel(const int* __restrict__ tke,
    int* __restrict__ meta, int* __restrict__ rowof, int* __restrict__ tokrow) {
  __shared__ int s_cnt[NE], s_base[NE];
  const int t = blockIdx.x * 256 + threadIdx.x;
  if (threadIdx.x < NE) s_cnt[threadIdx.x] = 0;
  __syncthreads();
  const int e0 = tke[t*2], e1 = tke[t*2 + 1];
  const int l0 = atomicAdd(&s_cnt[e0], 1);
  const int l1 = atomicAdd(&s_cnt[e1], 1);
  __syncthreads();
  if (threadIdx.x < NE)
    s_base[threadIdx.x] = atomicAdd(&meta[IDX_CUR + threadIdx.x], s_cnt[threadIdx.x]);
  __syncthreads();
  const int r0 = meta[IDX_OFF + e0] + s_base[e0] + l0;
  const int r1 = meta[IDX_OFF + e1] + s_base[e1] + l1;
  rowof[t*2]     = r0;
  rowof[t*2 + 1] = r1;
  tokrow[r0] = t;
  tokrow[r1] = t;
}

// ---------------- gather x rows -> bf16 Xg (zeros for padding) ------------
__global__ __launch_bounds__(192) void gather_kernel(const float* __restrict__ x,
    const int* __restrict__ tokrow, const int* __restrict__ meta,
    __bf16* __restrict__ Xg) {
  const int row = blockIdx.x;
  if (row >= meta[IDX_OFF + NE]) return;
  const int tok = tokrow[row];
  ushort4* dst = (ushort4*)(Xg + (size_t)row * DD);
  const int i = threadIdx.x;            // 192 threads x 4 elems = 768
  ushort4 o;
  if (tok >= 0) {
    float4 v = ((const float4*)(x + (size_t)tok * DD))[i];
    o.x = f2bf_bits(v.x); o.y = f2bf_bits(v.y);
    o.z = f2bf_bits(v.z); o.w = f2bf_bits(v.w);
  } else {
    o.x = o.y = o.z = o.w = 0;
  }
  dst[i] = o;
}

// ------------- transpose v2 (ALIGNED): float4 loads, 16B packed stores ----
// TS=68 -> LDS row stride 136 B: ushort4 stores at 136*r + 8*q are 8B-aligned
// for ALL r (round-4's TS=66 gave 4-mod-8 addresses for odd r => ds_write_b64 UB).
constexpr int TS = 68;
__global__ __launch_bounds__(256) void transpose_cvt_all(
    const float* __restrict__ w1, const float* __restrict__ w3,
    const float* __restrict__ w2, __bf16* __restrict__ W1t,
    __bf16* __restrict__ W3t, __bf16* __restrict__ W2t) {
  const int z = blockIdx.z, which = z >> 3, e = z & 7;
  const float* src; __bf16* dst; int R, C, rt, ct;
  if (which == 0)      { src = w1; dst = W1t; R = DD; C = FF; rt = blockIdx.y; ct = blockIdx.x; }
  else if (which == 1) { src = w3; dst = W3t; R = DD; C = FF; rt = blockIdx.y; ct = blockIdx.x; }
  else                 { src = w2; dst = W2t; R = FF; C = DD; rt = blockIdx.x; ct = blockIdx.y; }
  src += (size_t)e * DD * FF; dst += (size_t)e * DD * FF;
  const int r0 = rt * 64, c0 = ct * 64;
  __shared__ __align__(16) __bf16 tile[64 * TS];
  const int t = threadIdx.x;
  #pragma unroll
  for (int i = 0; i < 4; ++i) {                 // 1024 float4 = 64x64 fp32
    int idx = t + i * 256; int r = idx >> 4, q = idx & 15;
    float4 v = *(const float4*)&src[(size_t)(r0 + r) * C + c0 + q * 4];
    ushort4 o;
    o.x = f2bf_bits(v.x); o.y = f2bf_bits(v.y);
    o.z = f2bf_bits(v.z); o.w = f2bf_bits(v.w);
    *(ushort4*)&tile[r * TS + q * 4] = o;       // 8B-aligned (136r+8q)
  }
  __syncthreads();
  #pragma unroll
  for (int i = 0; i < 2; ++i) {                 // 512 ushort8 = 64x64 bf16
    int idx = t + i * 256; int c = idx >> 3, seg = idx & 7;
    u16x8 o;
    #pragma unroll
    for (int k = 0; k < 8; ++k)                 // scalar u16 LDS reads (aligned)
      o[k] = *(unsigned short*)&tile[(seg * 8 + k) * TS + c];
    *(u16x8*)&dst[(size_t)(c0 + c) * R + r0 + seg * 8] = o;  // 16B-aligned
  }
}

// ---------------- gemm1: H = silu(Xg@W1e) * (Xg@W3e) ----------------------
__global__ __launch_bounds__(256) void gemm1_kernel(const __bf16* __restrict__ Xg,
    const __bf16* __restrict__ W1t, const __bf16* __restrict__ W3t,
    __bf16* __restrict__ Hb, const int* __restrict__ meta) {
  const int mt = blockIdx.y;
  if (mt >= meta[IDX_NTILES]) return;
  const int e = meta[IDX_EXPT + mt];
  const int n0 = blockIdx.x * 64;
  const int m0 = mt * 128;
  __shared__ __align__(16) __bf16 As[128*32], B1s[64*32], B3s[64*32];
  const int t = threadIdx.x, wave = t >> 6, lane = t & 63;
  const __bf16* w1e = W1t + (size_t)e * FF * DD;  // [FF][DD]
  const __bf16* w3e = W3t + (size_t)e * FF * DD;
  const f32x4 zero = {0.f, 0.f, 0.f, 0.f};
  f32x4 acc1[2][4], acc3[2][4];
  #pragma unroll
  for (int i = 0; i < 2; ++i)
    #pragma unroll
    for (int j = 0; j < 4; ++j) { acc1[i][j] = zero; acc3[i][j] = zero; }

  const __bf16* gA  = Xg  + (size_t)(m0 + 32*wave + (lane >> 2)) * DD + (lane & 3) * 8;
  const __bf16* gB1 = w1e + (size_t)(n0 + 16*wave + (lane >> 2)) * DD + (lane & 3) * 8;
  const __bf16* gB3 = w3e + (size_t)(n0 + 16*wave + (lane >> 2)) * DD + (lane & 3) * 8;
  __bf16* lA0 = &As [(32*wave     ) * 32];
  __bf16* lA1 = &As [(32*wave + 16) * 32];
  __bf16* lB1 = &B1s[(16*wave     ) * 32];
  __bf16* lB3 = &B3s[(16*wave     ) * 32];

  for (int k0 = 0; k0 < DD; k0 += 32) {
    glds16(gA  + k0,           lA0);
    glds16(gA  + k0 + 16*DD,   lA1);
    glds16(gB1 + k0,           lB1);
    glds16(gB3 + k0,           lB3);
    __syncthreads();
    bf16x8v a[2], b1[4], b3[4];
    #pragma unroll
    for (int i = 0; i < 2; ++i)
      a[i] = *(const bf16x8v*)&As[(32*wave + 16*i + (lane & 15))*32 + (lane >> 4)*8];
    #pragma unroll
    for (int j = 0; j < 4; ++j) {
      b1[j] = *(const bf16x8v*)&B1s[(16*j + (lane & 15))*32 + (lane >> 4)*8];
      b3[j] = *(const bf16x8v*)&B3s[(16*j + (lane & 15))*32 + (lane >> 4)*8];
    }
    #pragma unroll
    for (int i = 0; i < 2; ++i)
      #pragma unroll
      for (int j = 0; j < 4; ++j) {
        acc1[i][j] = __builtin_amdgcn_mfma_f32_16x16x32_bf16(a[i], b1[j], acc1[i][j], 0, 0, 0);
        acc3[i][j] = __builtin_amdgcn_mfma_f32_16x16x32_bf16(a[i], b3[j], acc3[i][j], 0, 0, 0);
      }
    __syncthreads();
  }
  #pragma unroll
  for (int i = 0; i < 2; ++i) {
    const int rowb = m0 + 32*wave + 16*i + (lane >> 4)*4;
    #pragma unroll
    for (int j = 0; j < 4; ++j) {
      const int col = n0 + 16*j + (lane & 15);
      #pragma unroll
      for (int r = 0; r < 4; ++r) {
        float c1 = acc1[i][j][r], c3 = acc3[i][j][r];
        float h = c1 / (1.f + __expf(-c1)) * c3;   // silu(c1)*c3
        Hb[(size_t)(rowb + r)*FF + col] = (__bf16)h;
      }
    }
  }
}

// ---------------- gemm2: OP = H @ W2e; 128x128 m97-style ------------------
__global__ __launch_bounds__(256) void gemm2_kernel(const __bf16* __restrict__ Hb,
    const __bf16* __restrict__ W2t, __bf16* __restrict__ OP,
    const int* __restrict__ meta) {
  const int mt = blockIdx.y;
  if (mt >= meta[IDX_NTILES]) return;
  const int e = meta[IDX_EXPT + mt];
  const int n0 = blockIdx.x * 128;
  const int m0 = mt * 128;
  __shared__ __align__(16) __bf16 As[128*32], Bs[128*32];
  const int t = threadIdx.x, wave = t >> 6, lane = t & 63;
  const int wm = wave & 1, wn = wave >> 1;
  const __bf16* w2e = W2t + (size_t)e * DD * FF;  // [DD][FF]
  const f32x4 zero = {0.f, 0.f, 0.f, 0.f};
  f32x4 acc[4][4];
  #pragma unroll
  for (int i = 0; i < 4; ++i)
    #pragma unroll
    for (int j = 0; j < 4; ++j) acc[i][j] = zero;

  const __bf16* gA = Hb  + (size_t)(m0 + 32*wave + (lane >> 2)) * FF + (lane & 3) * 8;
  const __bf16* gB = w2e + (size_t)(n0 + 32*wave + (lane >> 2)) * FF + (lane & 3) * 8;
  __bf16* lA0 = &As[(32*wave     ) * 32];
  __bf16* lA1 = &As[(32*wave + 16) * 32];
  __bf16* lB0 = &Bs[(32*wave     ) * 32];
  __bf16* lB1 = &Bs[(32*wave + 16) * 32];

  for (int k0 = 0; k0 < FF; k0 += 32) {
    glds16(gA + k0,          lA0);
    glds16(gA + k0 + 16*FF,  lA1);
    glds16(gB + k0,          lB0);
    glds16(gB + k0 + 16*FF,  lB1);
    __syncthreads();
    bf16x8v a[4], b[4];
    #pragma unroll
    for (int i = 0; i < 4; ++i) {
      a[i] = *(const bf16x8v*)&As[(64*wm + 16*i + (lane & 15))*32 + (lane >> 4)*8];
      b[i] = *(const bf16x8v*)&Bs[(64*wn + 16*i + (lane & 15))*32 + (lane >> 4)*8];
    }
    #pragma unroll
    for (int i = 0; i < 4; ++i)
      #pragma unroll
      for (int j = 0; j < 4; ++j)
        acc[i][j] = __builtin_amdgcn_mfma_f32_16x16x32_bf16(a[i], b[j], acc[i][j], 0, 0, 0);
    __syncthreads();
  }
  #pragma unroll
  for (int i = 0; i < 4; ++i) {
    const int rowb = m0 + 64*wm + 16*i + (lane >> 4)*4;
    #pragma unroll
    for (int j = 0; j < 4; ++j) {
      const int col = n0 + 64*wn + 16*j + (lane & 15);
      #pragma unroll
      for (int r = 0; r < 4; ++r)
        OP[(size_t)(rowb + r)*DD + col] = (__bf16)acc[i][j][r];
    }
  }
}

// ---------------- combine: out[t] = g0*OP[row0] + g1*OP[row1] -------------
__global__ __launch_bounds__(192) void combine_kernel(const __bf16* __restrict__ OP,
    const int* __restrict__ rowof, const float* __restrict__ gateArr,
    float* __restrict__ out) {
  const int t = blockIdx.x;
  const int r0 = rowof[t*2], r1 = rowof[t*2 + 1];
  const float g0 = gateArr[t*2], g1 = gateArr[t*2 + 1];
  const ushort4* p0 = (const ushort4*)(OP + (size_t)r0 * DD);
  const ushort4* p1 = (const ushort4*)(OP + (size_t)r1 * DD);
  const int i = threadIdx.x;
  ushort4 a = p0[i], b = p1[i];
  float4 o;
  o.x = g0 * bf2f(a.x) + g1 * bf2f(b.x);
  o.y = g0 * bf2f(a.y) + g1 * bf2f(b.y);
  o.z = g0 * bf2f(a.z) + g1 * bf2f(b.z);
  o.w = g0 * bf2f(a.w) + g1 * bf2f(b.w);
  ((float4*)(out + (size_t)t * DD))[i] = o;
}

extern "C" void kernel_launch(void* const* d_in, const int* in_sizes, int n_in,
                              void* d_out, int out_size, void* d_ws, size_t ws_size,
                              hipStream_t stream) {
  const float* x  = (const float*)d_in[0];
  const float* rw = (const float*)d_in[1];
  const float* w1 = (const float*)d_in[2];
  const float* w2 = (const float*)d_in[3];
  const float* w3 = (const float*)d_in[4];
  float* out = (float*)d_out;

  char* ws = (char*)d_ws;
  int*    meta   = (int*)(ws + OFF_META);
  int*    tke    = (int*)(ws + OFF_TKE);
  float*  gateA  = (float*)(ws + OFF_GATE);
  int*    rowof  = (int*)(ws + OFF_ROWOF);
  int*    tokrow = (int*)(ws + OFF_TOKROW);
  __bf16* Xg     = (__bf16*)(ws + OFF_XG);
  __bf16* W1t    = (__bf16*)(ws + OFF_W1T);
  __bf16* W3t    = (__bf16*)(ws + OFF_W3T);
  __bf16* W2t    = (__bf16*)(ws + OFF_W2T);
  __bf16* Hb     = (__bf16*)(ws + OFF_H);
  __bf16* OP     = (__bf16*)(ws + OFF_OP);

  hipMemsetAsync(ws + OFF_META, 0, 1024, stream);
  hipMemsetAsync(ws + OFF_TOKROW, 0xFF, (size_t)MAXROWS * 4, stream);  // tok=-1

  transpose_cvt_all<<<dim3(32, 12, 24), 256, 0, stream>>>(w1, w3, w2, W1t, W3t, W2t);

  router_kernel<<<RB, 256, 0, stream>>>(x, rw, meta, tke, gateA);
  scan_kernel<<<1, 128, 0, stream>>>(meta, out + (size_t)NT * DD);
  scatter_kernel<<<NT/256, 256, 0, stream>>>(tke, meta, rowof, tokrow);
  gather_kernel<<<MAXROWS, 192, 0, stream>>>(x, tokrow, meta, Xg);

  gemm1_kernel<<<dim3(FF/64, MAXMT128), 256, 0, stream>>>(Xg, W1t, W3t, Hb, meta);
  gemm2_kernel<<<dim3(DD/128, MAXMT128), 256, 0, stream>>>(Hb, W2t, OP, meta);
  combine_kernel<<<NT, 192, 0, stream>>>(OP, rowof, gateA, out);
}